// Round 2
// baseline (83333.899 us; speedup 1.0000x reference)
//
#include <hip/hip_runtime.h>

#define NB 256
#define NT 1024

#define Bv 512
#define Tv 256
#define XDv 128
#define Hv 512
#define DDv 16
#define Pv 32

typedef short s8 __attribute__((ext_vector_type(8)));
typedef float f4 __attribute__((ext_vector_type(4)));

// ---- ws float offsets ----
#define OFF_H0   64
#define OFF_H1   (OFF_H0 + Bv*Hv)
#define OFF_XH   (OFF_H1 + Bv*Hv)
#define OFF_KEYP (OFF_XH + Bv*XDv)
#define OFF_VALP (OFF_KEYP + Pv*Hv)
#define OFF_MF   (OFF_VALP + Pv*Hv)
#define OFF_C    (OFF_MF + Pv*Hv)
#define OFF_VWG  (OFF_C + 32)
#define OFF_SWZ  (OFF_VWG + 32)   // = 639104 floats; 16B aligned

// ---- swizzled bf16 buffers (ushort element offsets) ----
#define US_WHH  0
#define US_WIH  (US_WHH + 96*16*512)
#define US_WDT  (US_WIH + 96*9*512)
#define US_WHT  (US_WDT + 32*4*512)
#define US_WFT  (US_WHT + 8*16*512)
#define US_MS   (US_WFT + 8*4*512)
#define US_VALP (US_MS  + 2*16*512)

// ---- out offsets ----
#define OUT_HS  0
#define OUT_HN  (Bv*Tv*Hv)
#define OUT_XCS (OUT_HN + Bv*Hv)
#define OUT_ZCS (OUT_XCS + Bv*Tv*XDv)

struct Smem {
  unsigned short hA[32*520];    // h bf16, pitch 520
  unsigned short hpA[32*520];   // h' bf16
  unsigned short tA[32*136];    // times(t) bf16
  unsigned short xcA[32*136];   // x_c bf16
  unsigned short inpA[32*296];  // [z_c | m | static | pad] bf16
  unsigned short aA[32*40];     // unnormalized exp scores bf16
  float sc[32*33];              // raw score dots
  float ghS[3*32*33];
  float gxS[3*32*33];
  float hp32[32*32];            // h' f32, this block's col tile
  float ahS[32];
  float rsm[32];
  float al[32];
};

__device__ __forceinline__ unsigned short f2b(float f) {
  union { float f; unsigned int u; } x{f};
  unsigned int r = x.u + 0x7fffu + ((x.u >> 16) & 1u);
  return (unsigned short)(r >> 16);
}
__device__ __forceinline__ float b2f(unsigned short u) {
  union { unsigned int u; float f; } x{(unsigned int)u << 16};
  return x.f;
}
__device__ __forceinline__ float sig_f(float x) { return 1.f / (1.f + __expf(-x)); }
__device__ __forceinline__ float tanh_f(float x) {
  x = fminf(fmaxf(x, -15.f), 15.f);
  float e = __expf(2.f * x);
  return (e - 1.f) / (e + 1.f);
}

__device__ __forceinline__ void gridbar(unsigned int* bar, unsigned int& lgen) {
  __syncthreads();
  if (threadIdx.x == 0) {
    __threadfence();
    unsigned int target = ++lgen;
    unsigned int prev = __hip_atomic_fetch_add(&bar[0], 1u, __ATOMIC_ACQ_REL, __HIP_MEMORY_SCOPE_AGENT);
    if (prev == (unsigned)(NB - 1)) {
      __hip_atomic_store(&bar[0], 0u, __ATOMIC_RELAXED, __HIP_MEMORY_SCOPE_AGENT);
      __hip_atomic_store(&bar[1], target, __ATOMIC_RELEASE, __HIP_MEMORY_SCOPE_AGENT);
    } else {
      while (__hip_atomic_load(&bar[1], __ATOMIC_ACQUIRE, __HIP_MEMORY_SCOPE_AGENT) < target)
        __builtin_amdgcn_s_sleep(8);
    }
    __threadfence();
  }
  __syncthreads();
}

// build swizzled bf16 B-operand buffers: lane=(n&15)+16*((k>>3)&3), e=k&7
#define SWZ(DST, NTILES, KT_, EXPR)                                            \
  { const int tot = (NTILES)*(KT_)*512;                                        \
    for (int f = gtid; f < tot; f += NB*NT) {                                  \
      const int e = f & 7, lane_ = (f >> 3) & 63, rem = f >> 9;                \
      const int kt = rem % (KT_), nt = rem / (KT_);                            \
      const int n = nt*16 + (lane_ & 15);                                      \
      const int k = kt*32 + ((lane_ >> 4) & 3)*8 + e;                          \
      (DST)[f] = f2b((EXPR));                                                  \
    } }

#define MFMA(a,b,c) __builtin_amdgcn_mfma_f32_16x16x32_bf16((a),(b),(c),0,0,0)

__global__ __launch_bounds__(NT, 1)
void rits_main(const float* __restrict__ values, const int* __restrict__ lens,
               const float* __restrict__ statc, const float* __restrict__ times,
               const float* __restrict__ masks, const float* __restrict__ prototype,
               const int* __restrict__ protoflag,
               const float* __restrict__ Wd, const float* __restrict__ bd,
               const float* __restrict__ Wh, const float* __restrict__ bh,
               const float* __restrict__ Wf, const float* __restrict__ bf,
               const float* __restrict__ Wq, const float* __restrict__ bq,
               const float* __restrict__ Wk, const float* __restrict__ bk,
               const float* __restrict__ Wv, const float* __restrict__ bv,
               const float* __restrict__ Wg, const float* __restrict__ bg,
               const float* __restrict__ Wih, const float* __restrict__ Whh,
               const float* __restrict__ bih, const float* __restrict__ bhh,
               float* __restrict__ out, float* __restrict__ ws)
{
  const int bid = blockIdx.x, tid = threadIdx.x;
  const int gtid = bid*NT + tid;
  const int wave = tid >> 6, lane = tid & 63;
  const int rg = bid >> 4, cg = bid & 15;
  const int r0 = rg*32, c0 = cg*32;
  unsigned int* bar = (unsigned int*)ws;
  unsigned int lgen = 0;
  unsigned short* usb = (unsigned short*)(ws + OFF_SWZ);
  const unsigned short* WHHp = usb + US_WHH;
  const unsigned short* WIHp = usb + US_WIH;
  const unsigned short* WDTp = usb + US_WDT;
  const unsigned short* WHTp = usb + US_WHT;
  const unsigned short* WFTp = usb + US_WFT;
  const unsigned short* MSp  = usb + US_MS;
  const unsigned short* VALPp= usb + US_VALP;
  float* w_xh = ws + OFF_XH;

  __shared__ Smem L;
  const bool proto = protoflag[0] != 0;
  const float scale = 0.17677669529663687f;  // 1/sqrt(32)

  // ================= INIT 1 =================
  for (int i = gtid; i < 2*Bv*Hv + Bv*XDv; i += NB*NT) ws[OFF_H0 + i] = 0.f;
  for (int o = gtid; o < 2*Pv*Hv; o += NB*NT) {
    const int which = o >> 14, rem = o & 16383;
    const int p = rem >> 9, j = rem & 511;
    const float* W = which ? Wv : Wk;
    const float* bb = which ? bv : bk;
    const float* pr = prototype + p*Hv;
    const float* wr = W + j*Hv;
    float s = bb[j];
    #pragma unroll 4
    for (int k = 0; k < Hv; ++k) s += pr[k]*wr[k];
    ws[(which ? OFF_VALP : OFF_KEYP) + p*Hv + j] = s;
  }
  SWZ(usb+US_WHH, 96, 16, Whh[n*512 + k])
  SWZ(usb+US_WIH, 96, 9,  (k < 272 ? Wih[n*272 + k] : 0.f))
  SWZ(usb+US_WDT, 32, 4,  Wd[n*128 + k])
  SWZ(usb+US_WHT, 8, 16,  Wh[n*512 + k])
  SWZ(usb+US_WFT, 8, 4,   (n == k ? 0.f : Wf[n*128 + k]))
  gridbar(bar, lgen);

  // ================= INIT 2 =================
  {
    const float* keyp = ws + OFF_KEYP;
    const float* valp = ws + OFF_VALP;
    for (int o = gtid; o < Pv*Hv; o += NB*NT) {
      const int p = o >> 9, kc = o & 511;
      float s = 0.f;
      #pragma unroll 4
      for (int j = 0; j < Hv; ++j) s += keyp[p*Hv + j]*Wq[j*Hv + kc];
      ws[OFF_MF + o] = s;
    }
    if (gtid < 32) {
      float s = 0.f;
      for (int j = 0; j < Hv; ++j) s += bq[j]*keyp[gtid*Hv + j];
      ws[OFF_C + gtid] = s;
    } else if (gtid < 64) {
      const int p = gtid - 32;
      float s = 0.f;
      for (int j = 0; j < Hv; ++j) s += valp[p*Hv + j]*Wg[Hv + j];
      ws[OFF_VWG + p] = s;
    }
    SWZ(usb+US_VALP, 32, 1, (ws + OFF_VALP)[k*Hv + n])
  }
  gridbar(bar, lgen);

  // ================= INIT 3 =================
  SWZ(usb+US_MS, 2, 16, (ws + OFF_MF)[n*Hv + k])
  gridbar(bar, lgen);

  // ================= MAIN LOOP =================
  for (int t = 0; t < Tv; ++t) {
    const float* hcur = ws + ((t & 1) ? OFF_H1 : OFF_H0);
    float*       hnxt = ws + ((t & 1) ? OFF_H0 : OFF_H1);

    // ---- 1a: stage h -> hA bf16; times(t) -> tA bf16 ----
    {
      const int row = tid >> 5, k16 = (tid & 31)*16;
      const float* src = hcur + (size_t)(r0 + row)*Hv + k16;
      s8 v0, v1;
      #pragma unroll
      for (int q = 0; q < 8; ++q) {
        v0[q] = (short)f2b(src[q]);
        v1[q] = (short)f2b(src[q + 8]);
      }
      *(s8*)&L.hA[row*520 + k16]     = v0;
      *(s8*)&L.hA[row*520 + k16 + 8] = v1;
    }
    {
      const int row = tid >> 5, x4 = (tid & 31)*4;
      const float* tsrc = times + ((size_t)(r0 + row)*Tv + t)*XDv + x4;
      #pragma unroll
      for (int q = 0; q < 4; ++q) L.tA[row*136 + x4 + q] = f2b(tsrc[q]);
    }
    __syncthreads();

    // ---- 1b: gamma MFMA (waves 4-11), score MFMA (0-3), ah (12-15) ----
    f4 gam[8];
    if (wave >= 4 && wave < 12) {
      const int widx = wave - 4, rt = widx >> 2, ntg = widx & 3;
      const int arow = (rt*16 + (lane & 15))*136;
      #pragma unroll
      for (int q = 0; q < 8; ++q) {
        const int nt = ntg*8 + q;
        f4 acc = {0.f, 0.f, 0.f, 0.f};
        #pragma unroll
        for (int kt = 0; kt < 4; ++kt) {
          s8 a = *(const s8*)&L.tA[arow + kt*32 + (lane >> 4)*8];
          s8 b = *(const s8*)&WDTp[((size_t)(nt*4 + kt)*64 + lane)*8];
          acc = MFMA(a, b, acc);
        }
        const int col = nt*16 + (lane & 15);
        const float bdv = bd[col];
        #pragma unroll
        for (int i = 0; i < 4; ++i)
          gam[q][i] = __expf(-fmaxf(acc[i] + bdv, 0.f));
      }
    } else if (proto && wave < 4) {
      const int rt = wave >> 1, nt = wave & 1;
      const int arow = (rt*16 + (lane & 15))*520;
      f4 acc = {0.f, 0.f, 0.f, 0.f};
      #pragma unroll
      for (int kt = 0; kt < 16; ++kt) {
        s8 a = *(const s8*)&L.hA[arow + kt*32 + (lane >> 4)*8];
        s8 b = *(const s8*)&MSp[((size_t)(nt*16 + kt)*64 + lane)*8];
        acc = MFMA(a, b, acc);
      }
      const int col = nt*16 + (lane & 15);
      const int rb = rt*16 + (lane >> 4)*4;
      #pragma unroll
      for (int i = 0; i < 4; ++i) L.sc[(rb + i)*33 + col] = acc[i];
    } else if (proto && wave >= 12) {
      const int rho = (wave - 12)*64 + lane;
      const int row = rho >> 3, seg = rho & 7;
      const int kb = seg*64;
      float s = 0.f;
      #pragma unroll 8
      for (int k = 0; k < 64; ++k) s += b2f(L.hA[row*520 + kb + k]) * Wg[kb + k];
      s += __shfl_xor(s, 1); s += __shfl_xor(s, 2); s += __shfl_xor(s, 4);
      if (seg == 0) L.ahS[row] = s;
    }
    __syncthreads();

    // ---- 1c: softmax + alpha (wave 0, lanes 0-31) ----
    if (proto && wave == 0 && lane < 32) {
      const int r = lane;
      const float* cW = ws + OFF_C;
      const float* vwgW = ws + OFF_VWG;
      float mx = -1e30f;
      #pragma unroll 8
      for (int p = 0; p < 32; ++p)
        mx = fmaxf(mx, (L.sc[r*33 + p] + cW[p]) * scale);
      float sm = 0.f, a1 = 0.f;
      #pragma unroll 8
      for (int p = 0; p < 32; ++p) {
        float e = __expf((L.sc[r*33 + p] + cW[p]) * scale - mx);
        sm += e; a1 += e * vwgW[p];
        L.aA[r*40 + p] = f2b(e);
      }
      const float rs = 1.f / sm;
      L.rsm[r] = rs;
      L.al[r] = sig_f(L.ahS[r] + a1*rs + bg[0]);
    }
    __syncthreads();

    // ---- 1d: h1 MFMA + blend -> hpA (bf16), hp32 (f32 tile) ----
    if (wave >= 4 && wave < 12) {
      const int widx = wave - 4, rt = widx >> 2, ntg = widx & 3;
      #pragma unroll
      for (int q = 0; q < 8; ++q) {
        const int nt = ntg*8 + q;
        const int col = nt*16 + (lane & 15);
        f4 h1 = {0.f, 0.f, 0.f, 0.f};
        if (proto) {
          s8 a = *(const s8*)&L.aA[(rt*16 + (lane & 15))*40 + (lane >> 4)*8];
          s8 b = *(const s8*)&VALPp[((size_t)nt*64 + lane)*8];
          h1 = MFMA(a, b, h1);
        }
        #pragma unroll
        for (int i = 0; i < 4; ++i) {
          const int row = rt*16 + (lane >> 4)*4 + i;
          const float hv = hcur[(size_t)(r0 + row)*Hv + col];
          float hp;
          if (proto) {
            const float av = L.al[row];
            hp = (av*hv + (1.f - av)*h1[i]*L.rsm[row]) * gam[q][i];
          } else {
            hp = hv * gam[q][i];
          }
          L.hpA[row*520 + col] = f2b(hp);
          const unsigned cc = (unsigned)(col - c0);
          if (cc < 32u) L.hp32[row*32 + cc] = hp;
        }
      }
    }
    __syncthreads();

    // ---- 1e: x_h MFMA + x_c ----
    float xv[4], mv[4];
    {
      const int rt = wave >> 3, nt = wave & 7;
      const int col = nt*16 + (lane & 15);
      const int arow = (rt*16 + (lane & 15))*520;
      f4 acc = {0.f, 0.f, 0.f, 0.f};
      #pragma unroll
      for (int kt = 0; kt < 16; ++kt) {
        s8 a = *(const s8*)&L.hpA[arow + kt*32 + (lane >> 4)*8];
        s8 b = *(const s8*)&WHTp[((size_t)(nt*16 + kt)*64 + lane)*8];
        acc = MFMA(a, b, acc);
      }
      const float bhv = bh[col];
      #pragma unroll
      for (int i = 0; i < 4; ++i) {
        const int row = rt*16 + (lane >> 4)*4 + i;
        const int b = r0 + row;
        const bool valid = t < lens[b];
        float xh = acc[i] + bhv;
        if (valid) w_xh[b*XDv + col] = xh;
        else       xh = w_xh[b*XDv + col];
        const size_t xo = ((size_t)b*Tv + t)*XDv + col;
        xv[i] = values[xo]; mv[i] = masks[xo];
        const float xc = mv[i]*xv[i] + (1.f - mv[i])*xh;
        if (cg == 0) out[OUT_XCS + xo] = xc;
        L.xcA[row*136 + col] = f2b(xc);
      }
    }
    __syncthreads();

    // ---- 1f: z_h MFMA + z_c -> inpA ----
    {
      const int rt = wave >> 3, nt = wave & 7;
      const int col = nt*16 + (lane & 15);
      const int arow = (rt*16 + (lane & 15))*136;
      f4 acc = {0.f, 0.f, 0.f, 0.f};
      #pragma unroll
      for (int kt = 0; kt < 4; ++kt) {
        s8 a = *(const s8*)&L.xcA[arow + kt*32 + (lane >> 4)*8];
        s8 b = *(const s8*)&WFTp[((size_t)(nt*4 + kt)*64 + lane)*8];
        acc = MFMA(a, b, acc);
      }
      const float bfv = bf[col];
      #pragma unroll
      for (int i = 0; i < 4; ++i) {
        const int row = rt*16 + (lane >> 4)*4 + i;
        const int b = r0 + row;
        const size_t xo = ((size_t)b*Tv + t)*XDv + col;
        const float zc = mv[i]*xv[i] + (1.f - mv[i])*(acc[i] + bfv);
        if (cg == 0) out[OUT_ZCS + xo] = zc;
        L.inpA[row*296 + col]       = f2b(zc);
        L.inpA[row*296 + 128 + col] = f2b(mv[i]);
      }
    }
    if (tid < 512) {
      const int row = tid >> 4, cc2 = tid & 15;
      L.inpA[row*296 + 256 + cc2] = f2b(statc[(r0 + row)*DDv + cc2]);
    } else {
      const int t2 = tid - 512;
      const int row = t2 >> 4, cc2 = t2 & 15;
      L.inpA[row*296 + 272 + cc2] = 0;
    }
    __syncthreads();

    // ---- 2a: gh (waves 0-5) + gx (waves 6-11) MFMA strips ----
    if (wave < 6) {
      const int g = wave >> 1, hf = wave & 1;
      const int ntG = g*32 + cg*2 + hf;
      const int ar0 = (lane & 15)*520, ar1 = (16 + (lane & 15))*520;
      f4 acc0 = {0.f,0.f,0.f,0.f}, acc1 = {0.f,0.f,0.f,0.f};
      #pragma unroll
      for (int kt = 0; kt < 16; ++kt) {
        s8 b  = *(const s8*)&WHHp[((size_t)(ntG*16 + kt)*64 + lane)*8];
        s8 a0 = *(const s8*)&L.hpA[ar0 + kt*32 + (lane >> 4)*8];
        s8 a1 = *(const s8*)&L.hpA[ar1 + kt*32 + (lane >> 4)*8];
        acc0 = MFMA(a0, b, acc0);
        acc1 = MFMA(a1, b, acc1);
      }
      const int colL = hf*16 + (lane & 15);
      #pragma unroll
      for (int i = 0; i < 4; ++i) {
        const int rr = (lane >> 4)*4 + i;
        L.ghS[g*1056 + rr*33 + colL]        = acc0[i];
        L.ghS[g*1056 + (rr + 16)*33 + colL] = acc1[i];
      }
    } else if (wave < 12) {
      const int w2 = wave - 6, g = w2 >> 1, hf = w2 & 1;
      const int ntG = g*32 + cg*2 + hf;
      const int ar0 = (lane & 15)*296, ar1 = (16 + (lane & 15))*296;
      f4 acc0 = {0.f,0.f,0.f,0.f}, acc1 = {0.f,0.f,0.f,0.f};
      #pragma unroll
      for (int kt = 0; kt < 9; ++kt) {
        s8 b  = *(const s8*)&WIHp[((size_t)(ntG*9 + kt)*64 + lane)*8];
        s8 a0 = *(const s8*)&L.inpA[ar0 + kt*32 + (lane >> 4)*8];
        s8 a1 = *(const s8*)&L.inpA[ar1 + kt*32 + (lane >> 4)*8];
        acc0 = MFMA(a0, b, acc0);
        acc1 = MFMA(a1, b, acc1);
      }
      const int colL = hf*16 + (lane & 15);
      #pragma unroll
      for (int i = 0; i < 4; ++i) {
        const int rr = (lane >> 4)*4 + i;
        L.gxS[g*1056 + rr*33 + colL]        = acc0[i];
        L.gxS[g*1056 + (rr + 16)*33 + colL] = acc1[i];
      }
    }
    __syncthreads();

    // ---- 2b: GRU cell + writes ----
    {
      const int row = tid >> 5, jj = tid & 31;
      const int b = r0 + row, jc = c0 + jj;
      const float xr = L.gxS[row*33 + jj]        + bih[jc];
      const float xz = L.gxS[1056 + row*33 + jj] + bih[512 + jc];
      const float xn = L.gxS[2112 + row*33 + jj] + bih[1024 + jc];
      const float hr = L.ghS[row*33 + jj]        + bhh[jc];
      const float hz = L.ghS[1056 + row*33 + jj] + bhh[512 + jc];
      const float hn = L.ghS[2112 + row*33 + jj] + bhh[1024 + jc];
      const float r = sig_f(xr + hr), z = sig_f(xz + hz);
      const float n = tanh_f(xn + r*hn);
      const float hpv = L.hp32[row*32 + jj];
      const float hfv = (t < lens[b]) ? ((1.f - z)*n + z*hpv) : hpv;
      hnxt[(size_t)b*Hv + jc] = hfv;
      out[OUT_HS + ((size_t)b*Tv + t)*Hv + jc] = hfv;
      if (t == Tv - 1) out[OUT_HN + (size_t)b*Hv + jc] = hfv;
    }
    gridbar(bar, lgen);
  }
}

extern "C" void kernel_launch(void* const* d_in, const int* in_sizes, int n_in,
                              void* d_out, int out_size, void* d_ws, size_t ws_size,
                              hipStream_t stream) {
  (void)in_sizes; (void)n_in; (void)out_size; (void)ws_size;
  hipMemsetAsync(d_ws, 0, 256, stream);
  rits_main<<<NB, NT, 0, stream>>>(
      (const float*)d_in[0],  (const int*)d_in[1],   (const float*)d_in[2],
      (const float*)d_in[3],  (const float*)d_in[4], (const float*)d_in[5],
      (const int*)d_in[6],
      (const float*)d_in[7],  (const float*)d_in[8],
      (const float*)d_in[9],  (const float*)d_in[10],
      (const float*)d_in[11], (const float*)d_in[12],
      (const float*)d_in[13], (const float*)d_in[14],
      (const float*)d_in[15], (const float*)d_in[16],
      (const float*)d_in[17], (const float*)d_in[18],
      (const float*)d_in[19], (const float*)d_in[20],
      (const float*)d_in[21], (const float*)d_in[22],
      (const float*)d_in[23], (const float*)d_in[24],
      (float*)d_out, (float*)d_ws);
}

// Round 3
// 28931.613 us; speedup vs baseline: 2.8804x; 2.8804x over previous
//
#include <hip/hip_runtime.h>

#define NB 256
#define NT 1024

#define Bv 512
#define Tv 256
#define XDv 128
#define Hv 512
#define DDv 16
#define Pv 32

typedef short s8 __attribute__((ext_vector_type(8)));
typedef float f4 __attribute__((ext_vector_type(4)));

#define OFF_KEYP 64
#define OFF_VALP (OFF_KEYP + Pv*Hv)
#define OFF_MF   (OFF_VALP + Pv*Hv)
#define OFF_C    (OFF_MF + Pv*Hv)
#define OFF_VWG  (OFF_C + 32)
#define OFF_H0   (OFF_VWG + 32)
#define OFF_H1   (OFF_H0 + Bv*Hv)
#define OFF_XH   (OFF_H1 + Bv*Hv)

#define OUT_HS  0
#define OUT_HN  (Bv*Tv*Hv)
#define OUT_XCS (OUT_HN + Bv*Hv)
#define OUT_ZCS (OUT_XCS + Bv*Tv*XDv)

struct Smem {
  unsigned short hA[32*520];
  unsigned short hpA[32*520];
  unsigned short tA[32*136];
  unsigned short xcA[32*136];
  unsigned short inpA[32*296];
  unsigned short aA[32*40];
  float sc[32*33];
  float ghS[3*32*33];
  float gxS[3*32*33];
  float hp32[32*32];
  float ahS[32];
  float rsm[32];
  float al[32];
  float cS[32];
  float vwgS[32];
};

__device__ __forceinline__ unsigned short f2b(float f) {
  union { float f; unsigned int u; } x{f};
  unsigned int r = x.u + 0x7fffu + ((x.u >> 16) & 1u);
  return (unsigned short)(r >> 16);
}
__device__ __forceinline__ float b2f(unsigned short u) {
  union { unsigned int u; float f; } x{(unsigned int)u << 16};
  return x.f;
}
__device__ __forceinline__ float sig_f(float x) { return 1.f / (1.f + __expf(-x)); }
__device__ __forceinline__ float tanh_f(float x) {
  x = fminf(fmaxf(x, -15.f), 15.f);
  float e = __expf(2.f * x);
  return (e - 1.f) / (e + 1.f);
}

__device__ __forceinline__ void gridbar(unsigned int* bar, unsigned int& lgen) {
  __syncthreads();
  if (threadIdx.x == 0) {
    __threadfence();
    const unsigned int target = ++lgen;
    const unsigned int prev =
        __hip_atomic_fetch_add(&bar[0], 1u, __ATOMIC_RELAXED, __HIP_MEMORY_SCOPE_AGENT);
    if (prev == (unsigned)(NB - 1)) {
      __hip_atomic_store(&bar[0], 0u, __ATOMIC_RELAXED, __HIP_MEMORY_SCOPE_AGENT);
      __hip_atomic_store(&bar[1], target, __ATOMIC_RELEASE, __HIP_MEMORY_SCOPE_AGENT);
    } else {
      while (__hip_atomic_load(&bar[1], __ATOMIC_RELAXED, __HIP_MEMORY_SCOPE_AGENT) < target)
        __builtin_amdgcn_s_sleep(2);
    }
    __threadfence();
  }
  __syncthreads();
}

__device__ __forceinline__ s8 pack8(const float* p) {
  f4 a = *(const f4*)p; f4 b = *(const f4*)(p + 4);
  s8 r;
  r[0]=(short)f2b(a[0]); r[1]=(short)f2b(a[1]); r[2]=(short)f2b(a[2]); r[3]=(short)f2b(a[3]);
  r[4]=(short)f2b(b[0]); r[5]=(short)f2b(b[1]); r[6]=(short)f2b(b[2]); r[7]=(short)f2b(b[3]);
  return r;
}

#define MFMA(a,b,c) __builtin_amdgcn_mfma_f32_16x16x32_bf16((a),(b),(c),0,0,0)

__global__ __launch_bounds__(NT) __attribute__((amdgpu_waves_per_eu(4, 4)))
void rits_main(const float* __restrict__ values, const int* __restrict__ lens,
               const float* __restrict__ statc, const float* __restrict__ times,
               const float* __restrict__ masks, const float* __restrict__ prototype,
               const int* __restrict__ protoflag,
               const float* __restrict__ Wd, const float* __restrict__ bd,
               const float* __restrict__ Wh, const float* __restrict__ bh,
               const float* __restrict__ Wf, const float* __restrict__ bf,
               const float* __restrict__ Wq, const float* __restrict__ bq,
               const float* __restrict__ Wk, const float* __restrict__ bk,
               const float* __restrict__ Wv, const float* __restrict__ bv,
               const float* __restrict__ Wg, const float* __restrict__ bg,
               const float* __restrict__ Wih, const float* __restrict__ Whh,
               const float* __restrict__ bih, const float* __restrict__ bhh,
               float* __restrict__ out, float* __restrict__ ws)
{
  const int bid = blockIdx.x, tid = threadIdx.x;
  const int gtid = bid*NT + tid;
  const int wv = tid >> 6, ln = tid & 63;
  const int l15 = ln & 15, l4 = ln >> 4;
  const int rg = bid >> 4, cg = bid & 15;
  const int r0 = rg*32, c0 = cg*32;
  unsigned int* bar = (unsigned int*)ws;
  unsigned int lgen = 0;

  __shared__ Smem L;
  const bool proto = protoflag[0] != 0;
  const float scale = 0.17677669529663687f;

  for (int i = gtid; i < 2*Bv*Hv + Bv*XDv; i += NB*NT) ws[OFF_H0 + i] = 0.f;
  for (int o = gtid; o < 2*Pv*Hv; o += NB*NT) {
    const int which = o >> 14, rem = o & 16383;
    const int p = rem >> 9, j = rem & 511;
    const float* W = which ? Wv : Wk;
    const float* bb = which ? bv : bk;
    const float* pr = prototype + p*Hv;
    const float* wr = W + j*Hv;
    float s = bb[j];
    #pragma unroll 4
    for (int k = 0; k < Hv; ++k) s += pr[k]*wr[k];
    ws[(which ? OFF_VALP : OFF_KEYP) + p*Hv + j] = s;
  }
  gridbar(bar, lgen);

  {
    const float* keyp = ws + OFF_KEYP;
    const float* valp = ws + OFF_VALP;
    for (int o = gtid; o < Pv*Hv; o += NB*NT) {
      const int p = o >> 9, kc = o & 511;
      float s = 0.f;
      #pragma unroll 4
      for (int j = 0; j < Hv; ++j) s += keyp[p*Hv + j]*Wq[j*Hv + kc];
      ws[OFF_MF + o] = s;
    }
    if (gtid < 32) {
      float s = 0.f;
      for (int j = 0; j < Hv; ++j) s += bq[j]*keyp[gtid*Hv + j];
      ws[OFF_C + gtid] = s;
    } else if (gtid < 64) {
      const int p = gtid - 32;
      float s = 0.f;
      for (int j = 0; j < Hv; ++j) s += valp[p*Hv + j]*Wg[Hv + j];
      ws[OFF_VWG + p] = s;
    }
  }
  gridbar(bar, lgen);

  if (tid < 32) { L.cS[tid] = ws[OFF_C + tid]; L.vwgS[tid] = ws[OFF_VWG + tid]; }
  for (int o = tid; o < 32*40; o += NT) {
    const int row = o / 40, cc = o % 40;
    L.inpA[row*296 + 256 + cc] =
        (cc < DDv) ? f2b(statc[(r0 + row)*DDv + cc]) : (unsigned short)0;
  }

  const int grt = wv >> 3;
  s8 wdt[16]; s8 vp[4]; f4 bdv4;
  #pragma unroll
  for (int j = 0; j < 4; ++j) {
    const int nt = (wv & 7)*4 + j;
    const int n = nt*16 + l15;
    #pragma unroll
    for (int kt = 0; kt < 4; ++kt)
      wdt[j*4 + kt] = pack8(Wd + (size_t)n*XDv + kt*32 + l4*8);
    bdv4[j] = bd[n];
    const float* vb = ws + OFF_VALP;
    s8 r;
    #pragma unroll
    for (int e = 0; e < 8; ++e) r[e] = (short)f2b(vb[(size_t)(l4*8 + e)*Hv + n]);
    vp[j] = r;
  }
  const int xrt = wv >> 3, xnt = wv & 7;
  const int xcol = xnt*16 + l15;
  s8 wht[16]; s8 wft[4];
  #pragma unroll
  for (int kt = 0; kt < 16; ++kt)
    wht[kt] = pack8(Wh + (size_t)xcol*Hv + kt*32 + l4*8);
  #pragma unroll
  for (int kt = 0; kt < 4; ++kt) {
    const int k0 = kt*32 + l4*8;
    s8 r = pack8(Wf + (size_t)xcol*XDv + k0);
    #pragma unroll
    for (int e = 0; e < 8; ++e) if (xcol == k0 + e) r[e] = 0;
    wft[kt] = r;
  }
  const float bhv = bh[xcol], bfv = bf[xcol];
  int lens4[4];
  #pragma unroll
  for (int i = 0; i < 4; ++i) lens4[i] = lens[r0 + xrt*16 + l4*4 + i];

  s8 wA[16];
  if (wv < 12) {
    const int g = wv >> 2, hf = (wv >> 1) & 1;
    const int n = (g*32 + cg*2 + hf)*16 + l15;
    #pragma unroll
    for (int kt = 0; kt < 16; ++kt)
      wA[kt] = pack8(Whh + (size_t)n*Hv + kt*32 + l4*8);
  } else {
    const int n = ((wv - 12) & 1)*16 + l15;
    #pragma unroll
    for (int kt = 0; kt < 16; ++kt)
      wA[kt] = pack8(ws + OFF_MF + (size_t)n*Hv + kt*32 + l4*8);
  }
  s8 wih[9];
  if (wv >= 4) {
    const int w2 = wv - 4;
    const int g = w2 >> 2, hf = (w2 >> 1) & 1;
    const int n = (g*32 + cg*2 + hf)*16 + l15;
    #pragma unroll
    for (int kt = 0; kt < 9; ++kt) {
      const int k0 = kt*32 + l4*8;
      s8 r;
      #pragma unroll
      for (int e = 0; e < 8; ++e) r[e] = 0;
      if (k0 < 272) r = pack8(Wih + (size_t)n*272 + k0);
      wih[kt] = r;
    }
  }
  float wgr[8];
  if (wv < 4) {
    #pragma unroll
    for (int e = 0; e < 8; ++e) wgr[e] = Wg[ln*8 + e];
  }
  const int crow = tid >> 5, cjj = tid & 31;
  const int cb = r0 + crow, cjc = c0 + cjj;
  float bihR[3], bhhR[3];
  #pragma unroll
  for (int g = 0; g < 3; ++g) { bihR[g] = bih[g*Hv + cjc]; bhhR[g] = bhh[g*Hv + cjc]; }
  const int lensb = lens[cb];
  const float bg0 = bg[0];

  for (int t = 0; t < Tv; ++t) {
    const float* hcur = ws + ((t & 1) ? OFF_H1 : OFF_H0);
    float*       hnxt = ws + ((t & 1) ? OFF_H0 : OFF_H1);

    {
      const int row = tid >> 5, k16 = (tid & 31)*16;
      const float* src = hcur + (size_t)(r0 + row)*Hv + k16;
      *(s8*)&L.hA[row*520 + k16]     = pack8(src);
      *(s8*)&L.hA[row*520 + k16 + 8] = pack8(src + 8);
    }
    {
      const int row = tid >> 5, x4 = (tid & 31)*4;
      const float* ts = times + ((size_t)(r0 + row)*Tv + t)*XDv + x4;
      f4 v = *(const f4*)ts;
      #pragma unroll
      for (int q = 0; q < 4; ++q) L.tA[row*136 + x4 + q] = f2b(v[q]);
    }
    __syncthreads();

    f4 gam4[4];
    #pragma unroll
    for (int j = 0; j < 4; ++j) {
      const int arow = (grt*16 + l15)*136;
      f4 acc = {0.f,0.f,0.f,0.f};
      #pragma unroll
      for (int kt = 0; kt < 4; ++kt) {
        s8 a = *(const s8*)&L.tA[arow + kt*32 + l4*8];
        acc = MFMA(a, wdt[j*4 + kt], acc);
      }
      #pragma unroll
      for (int i = 0; i < 4; ++i)
        gam4[j][i] = __expf(-fmaxf(acc[i] + bdv4[j], 0.f));
    }
    if (proto) {
      if (wv >= 12) {
        const int job = wv - 12, srt = job >> 1, snt = job & 1;
        const int arow = (srt*16 + l15)*520;
        f4 acc = {0.f,0.f,0.f,0.f};
        #pragma unroll
        for (int kt = 0; kt < 16; ++kt) {
          s8 a = *(const s8*)&L.hA[arow + kt*32 + l4*8];
          acc = MFMA(a, wA[kt], acc);
        }
        const int pcol = snt*16 + l15;
        #pragma unroll
        for (int i = 0; i < 4; ++i)
          L.sc[(srt*16 + l4*4 + i)*33 + pcol] = acc[i];
      } else if (wv < 4) {
        #pragma unroll
        for (int rr = 0; rr < 8; ++rr) {
          const int row = wv*8 + rr;
          s8 hv8 = *(const s8*)&L.hA[row*520 + ln*8];
          float s = 0.f;
          #pragma unroll
          for (int e = 0; e < 8; ++e) s += b2f((unsigned short)hv8[e]) * wgr[e];
          s += __shfl_xor(s, 1);  s += __shfl_xor(s, 2);  s += __shfl_xor(s, 4);
          s += __shfl_xor(s, 8);  s += __shfl_xor(s, 16); s += __shfl_xor(s, 32);
          if (ln == 0) L.ahS[row] = s;
        }
      }
    }
    __syncthreads();

    if (proto && wv == 0 && ln < 32) {
      const int r = ln;
      float mx = -1e30f;
      #pragma unroll 8
      for (int p = 0; p < 32; ++p)
        mx = fmaxf(mx, (L.sc[r*33 + p] + L.cS[p]) * scale);
      float sm = 0.f, a1 = 0.f;
      #pragma unroll 8
      for (int p = 0; p < 32; ++p) {
        float e = __expf((L.sc[r*33 + p] + L.cS[p]) * scale - mx);
        sm += e; a1 += e * L.vwgS[p];
        L.aA[r*40 + p] = f2b(e);
      }
      const float rs = 1.f / sm;
      L.rsm[r] = rs;
      L.al[r] = sig_f(L.ahS[r] + a1*rs + bg0);
    }
    __syncthreads();

    #pragma unroll
    for (int j = 0; j < 4; ++j) {
      const int nt = (wv & 7)*4 + j;
      const int col = nt*16 + l15;
      f4 h1 = {0.f,0.f,0.f,0.f};
      if (proto) {
        s8 a = *(const s8*)&L.aA[(grt*16 + l15)*40 + l4*8];
        h1 = MFMA(a, vp[j], h1);
      }
      #pragma unroll
      for (int i = 0; i < 4; ++i) {
        const int row = grt*16 + l4*4 + i;
        const float hv = hcur[(size_t)(r0 + row)*Hv + col];
        float hp;
        if (proto) {
          const float av = L.al[row];
          hp = (av*hv + (1.f - av)*h1[i]*L.rsm[row]) * gam4[j][i];
        } else hp = hv * gam4[j][i];
        L.hpA[row*520 + col] = f2b(hp);
        const unsigned cc = (unsigned)(col - c0);
        if (cc < 32u) L.hp32[row*32 + cc] = hp;
      }
    }
    __syncthreads();

    float xv4[4], mv4[4];
    {
      const int arow = (xrt*16 + l15)*520;
      f4 acc = {0.f,0.f,0.f,0.f};
      #pragma unroll
      for (int kt = 0; kt < 16; ++kt) {
        s8 a = *(const s8*)&L.hpA[arow + kt*32 + l4*8];
        acc = MFMA(a, wht[kt], acc);
      }
      #pragma unroll
      for (int i = 0; i < 4; ++i) {
        const int row = xrt*16 + l4*4 + i;
        const int b = r0 + row;
        float xh = acc[i] + bhv;
        if (t < lens4[i]) {
          if (cg == 0) ws[OFF_XH + b*XDv + xcol] = xh;
        } else xh = ws[OFF_XH + b*XDv + xcol];
        const size_t xo = ((size_t)b*Tv + t)*XDv + xcol;
        xv4[i] = values[xo]; mv4[i] = masks[xo];
        const float xc = mv4[i]*xv4[i] + (1.f - mv4[i])*xh;
        if (cg == 0) out[OUT_XCS + xo] = xc;
        L.xcA[row*136 + xcol] = f2b(xc);
      }
    }
    __syncthreads();

    {
      const int arow = (xrt*16 + l15)*136;
      f4 acc = {0.f,0.f,0.f,0.f};
      #pragma unroll
      for (int kt = 0; kt < 4; ++kt) {
        s8 a = *(const s8*)&L.xcA[arow + kt*32 + l4*8];
        acc = MFMA(a, wft[kt], acc);
      }
      #pragma unroll
      for (int i = 0; i < 4; ++i) {
        const int row = xrt*16 + l4*4 + i;
        const size_t xo = ((size_t)(r0 + row)*Tv + t)*XDv + xcol;
        const float zc = mv4[i]*xv4[i] + (1.f - mv4[i])*(acc[i] + bfv);
        if (cg == 0) out[OUT_ZCS + xo] = zc;
        L.inpA[row*296 + xcol]       = f2b(zc);
        L.inpA[row*296 + 128 + xcol] = f2b(mv4[i]);
      }
    }
    __syncthreads();

    if (wv < 12) {
      const int g = wv >> 2, hf = (wv >> 1) & 1, rt = wv & 1;
      const int arow = (rt*16 + l15)*520;
      f4 acc = {0.f,0.f,0.f,0.f};
      #pragma unroll
      for (int kt = 0; kt < 16; ++kt) {
        s8 a = *(const s8*)&L.hpA[arow + kt*32 + l4*8];
        acc = MFMA(a, wA[kt], acc);
      }
      const int colL = hf*16 + l15;
      #pragma unroll
      for (int i = 0; i < 4; ++i)
        L.ghS[g*1056 + (rt*16 + l4*4 + i)*33 + colL] = acc[i];
    }
    if (wv >= 4) {
      const int w2 = wv - 4;
      const int g = w2 >> 2, hf = (w2 >> 1) & 1, rt = w2 & 1;
      const int arow = (rt*16 + l15)*296;
      f4 acc = {0.f,0.f,0.f,0.f};
      #pragma unroll
      for (int kt = 0; kt < 9; ++kt) {
        s8 a = *(const s8*)&L.inpA[arow + kt*32 + l4*8];
        acc = MFMA(a, wih[kt], acc);
      }
      const int colL = hf*16 + l15;
      #pragma unroll
      for (int i = 0; i < 4; ++i)
        L.gxS[g*1056 + (rt*16 + l4*4 + i)*33 + colL] = acc[i];
    }
    __syncthreads();

    {
      const float xr = L.gxS[crow*33 + cjj]        + bihR[0];
      const float xz = L.gxS[1056 + crow*33 + cjj] + bihR[1];
      const float xn = L.gxS[2112 + crow*33 + cjj] + bihR[2];
      const float hr = L.ghS[crow*33 + cjj]        + bhhR[0];
      const float hz = L.ghS[1056 + crow*33 + cjj] + bhhR[1];
      const float hn = L.ghS[2112 + crow*33 + cjj] + bhhR[2];
      const float r = sig_f(xr + hr), z = sig_f(xz + hz);
      const float n = tanh_f(xn + r*hn);
      const float hpv = L.hp32[crow*32 + cjj];
      const float hfv = (t < lensb) ? ((1.f - z)*n + z*hpv) : hpv;
      hnxt[(size_t)cb*Hv + cjc] = hfv;
      out[OUT_HS + ((size_t)cb*Tv + t)*Hv + cjc] = hfv;
      if (t == Tv - 1) out[OUT_HN + (size_t)cb*Hv + cjc] = hfv;
    }
    gridbar(bar, lgen);
  }
}

extern "C" void kernel_launch(void* const* d_in, const int* in_sizes, int n_in,
                              void* d_out, int out_size, void* d_ws, size_t ws_size,
                              hipStream_t stream) {
  (void)in_sizes; (void)n_in; (void)out_size; (void)ws_size;
  hipMemsetAsync(d_ws, 0, 256, stream);
  rits_main<<<NB, NT, 0, stream>>>(
      (const float*)d_in[0],  (const int*)d_in[1],   (const float*)d_in[2],
      (const float*)d_in[3],  (const float*)d_in[4], (const float*)d_in[5],
      (const int*)d_in[6],
      (const float*)d_in[7],  (const float*)d_in[8],
      (const float*)d_in[9],  (const float*)d_in[10],
      (const float*)d_in[11], (const float*)d_in[12],
      (const float*)d_in[13], (const float*)d_in[14],
      (const float*)d_in[15], (const float*)d_in[16],
      (const float*)d_in[17], (const float*)d_in[18],
      (const float*)d_in[19], (const float*)d_in[20],
      (const float*)d_in[21], (const float*)d_in[22],
      (const float*)d_in[23], (const float*)d_in[24],
      (float*)d_out, (float*)d_ws);
}

// Round 4
// 22452.638 us; speedup vs baseline: 3.7115x; 1.2886x over previous
//
#include <hip/hip_runtime.h>

#define NB 256
#define NT 512

#define Bv 512
#define Tv 256
#define XDv 128
#define Hv 512
#define DDv 16
#define Pv 32

typedef short s8 __attribute__((ext_vector_type(8)));
typedef float f4 __attribute__((ext_vector_type(4)));

// ---- ws float offsets ----
#define OFF_KEYP 1024
#define OFF_VALP (OFF_KEYP + 16384)
#define OFF_MF   (OFF_VALP + 16384)
#define OFF_C    (OFF_MF + 16384)
#define OFF_VWG  (OFF_C + 32)
#define OFF_SP   (OFF_VWG + 32)
#define SP_SZ    (16*16*32*34)          // [rg][cg][32 rows][34] f32 partials
#define OFF_HPX  (OFF_SP + SP_SZ)       // bf16 [16][32][512] h' exchange

// ---- out offsets ----
#define OUT_HS  0
#define OUT_HN  (Bv*Tv*Hv)
#define OUT_XCS (OUT_HN + Bv*Hv)
#define OUT_ZCS (OUT_XCS + Bv*Tv*XDv)

struct Smem {
  unsigned short hpA[32*520];   // full h' rows bf16 (staged from ws each step)
  unsigned short tA[32*136];    // times(t) bf16
  unsigned short xcA[32*136];   // x_c bf16
  unsigned short inpA[32*296];  // [z_c | m | static | 0pad] bf16
  unsigned short aA[32*40];     // exp(score) bf16
  unsigned short hTileB[32*40]; // h tile bf16 (A-frag for score partials)
  unsigned short wdF[8*64*8];   // Wd strip frags
  unsigned short vpF[2*64*8];   // valp strip frags
  unsigned short msF[2*64*8];   // M strip frags
  float xhS[32*128];            // persistent x_h state (this row-group)
  float hTile[32*33];           // h tile f32 (persistent across steps)
  float scS[32*34];             // summed scores (+ah at col 32)
  float h1S[32*33];
  float ghS[3*32*33];
  float gxS[3*32*33];
  float hp32[32*32];            // h' f32 own col-tile (GRU carry)
  float al[32], rsm[32], wgS[32], vwgS[32], cS[32];
};

__device__ __forceinline__ unsigned short f2b(float f) {
  union { float f; unsigned int u; } x{f};
  unsigned int r = x.u + 0x7fffu + ((x.u >> 16) & 1u);
  return (unsigned short)(r >> 16);
}
__device__ __forceinline__ float sig_f(float x) { return 1.f / (1.f + __expf(-x)); }
__device__ __forceinline__ float tanh_f(float x) {
  x = fminf(fmaxf(x, -15.f), 15.f);
  float e = __expf(2.f * x);
  return (e - 1.f) / (e + 1.f);
}

__device__ __forceinline__ s8 pack8(const float* p) {
  f4 a = *(const f4*)p; f4 b = *(const f4*)(p + 4);
  s8 r;
  r[0]=(short)f2b(a[0]); r[1]=(short)f2b(a[1]); r[2]=(short)f2b(a[2]); r[3]=(short)f2b(a[3]);
  r[4]=(short)f2b(b[0]); r[5]=(short)f2b(b[1]); r[6]=(short)f2b(b[2]); r[7]=(short)f2b(b[3]);
  return r;
}

// two-level grid barrier: 16 arrival lines + root; relaxed polls
__device__ __forceinline__ void gridbar(unsigned int* bar, unsigned int& lgen, int bid) {
  __syncthreads();
  if (threadIdx.x == 0) {
    __threadfence();
    const unsigned int target = ++lgen;
    unsigned int* grp = bar + (bid >> 4)*16;
    const unsigned int a =
        __hip_atomic_fetch_add(grp, 1u, __ATOMIC_ACQ_REL, __HIP_MEMORY_SCOPE_AGENT);
    if (a == 15u) {
      __hip_atomic_store(grp, 0u, __ATOMIC_RELAXED, __HIP_MEMORY_SCOPE_AGENT);
      const unsigned int r =
          __hip_atomic_fetch_add(bar + 256, 1u, __ATOMIC_ACQ_REL, __HIP_MEMORY_SCOPE_AGENT);
      if (r == 15u) {
        __hip_atomic_store(bar + 256, 0u, __ATOMIC_RELAXED, __HIP_MEMORY_SCOPE_AGENT);
        __hip_atomic_store(bar + 272, target, __ATOMIC_RELEASE, __HIP_MEMORY_SCOPE_AGENT);
      }
    }
    while (__hip_atomic_load(bar + 272, __ATOMIC_RELAXED, __HIP_MEMORY_SCOPE_AGENT) < target)
      __builtin_amdgcn_s_sleep(2);
    __threadfence();
  }
  __syncthreads();
}

#define MFMA(a,b,c) __builtin_amdgcn_mfma_f32_16x16x32_bf16((a),(b),(c),0,0,0)

__global__ __launch_bounds__(NT) __attribute__((amdgpu_waves_per_eu(2, 2)))
void rits_main(const float* __restrict__ values, const int* __restrict__ lens,
               const float* __restrict__ statc, const float* __restrict__ times,
               const float* __restrict__ masks, const float* __restrict__ prototype,
               const int* __restrict__ protoflag,
               const float* __restrict__ Wd, const float* __restrict__ bd,
               const float* __restrict__ Wh, const float* __restrict__ bh,
               const float* __restrict__ Wf, const float* __restrict__ bf,
               const float* __restrict__ Wq, const float* __restrict__ bq,
               const float* __restrict__ Wk, const float* __restrict__ bk,
               const float* __restrict__ Wv, const float* __restrict__ bv,
               const float* __restrict__ Wg, const float* __restrict__ bg,
               const float* __restrict__ Wih, const float* __restrict__ Whh,
               const float* __restrict__ bih, const float* __restrict__ bhh,
               float* __restrict__ out, float* __restrict__ ws)
{
  const int bid = blockIdx.x, tid = threadIdx.x;
  const int gtid = bid*NT + tid;
  const int wv = tid >> 6, ln = tid & 63;
  const int l15 = ln & 15, l4 = ln >> 4;
  const int rg = bid >> 4, cg = bid & 15;
  const int r0 = rg*32, c0 = cg*32;
  unsigned int* bar = (unsigned int*)ws;
  unsigned int lgen = 0;
  unsigned short* wsHP = (unsigned short*)(ws + OFF_HPX);
  float* wsSP = ws + OFF_SP;

  __shared__ Smem L;
  const bool proto = protoflag[0] != 0;
  const float scale = 0.17677669529663687f;

  // ============ INIT 1: keyp/valp + zero ws_sp ============
  for (int o = gtid; o < SP_SZ; o += NB*NT) wsSP[o] = 0.f;
  for (int o = gtid; o < 2*Pv*Hv; o += NB*NT) {
    const int which = o >> 14, rem = o & 16383;
    const int p = rem >> 9, j = rem & 511;
    const float* W = which ? Wv : Wk;
    const float* bb = which ? bv : bk;
    const float* pr = prototype + p*Hv;
    const float* wr = W + j*Hv;
    float s = bb[j];
    #pragma unroll 4
    for (int k = 0; k < Hv; ++k) s += pr[k]*wr[k];
    ws[(which ? OFF_VALP : OFF_KEYP) + p*Hv + j] = s;
  }
  gridbar(bar, lgen, bid);

  // ============ INIT 2: M = keyp@Wq, c, vwg ============
  {
    const float* keyp = ws + OFF_KEYP;
    const float* valp = ws + OFF_VALP;
    for (int o = gtid; o < Pv*Hv; o += NB*NT) {
      const int p = o >> 9, kc = o & 511;
      float s = 0.f;
      #pragma unroll 4
      for (int j = 0; j < Hv; ++j) s += keyp[p*Hv + j]*Wq[j*Hv + kc];
      ws[OFF_MF + o] = s;
    }
    if (gtid < 32) {
      float s = 0.f;
      for (int j = 0; j < Hv; ++j) s += bq[j]*keyp[gtid*Hv + j];
      ws[OFF_C + gtid] = s;
    } else if (gtid < 64) {
      const int p = gtid - 32;
      float s = 0.f;
      for (int j = 0; j < Hv; ++j) s += valp[p*Hv + j]*Wg[Hv + j];
      ws[OFF_VWG + p] = s;
    }
  }
  gridbar(bar, lgen, bid);

  // ============ block-local LDS init ============
  for (int o = tid; o < 32*33; o += NT) L.hTile[o] = 0.f;
  for (int o = tid; o < 32*128; o += NT) L.xhS[o] = 0.f;
  if (tid < 32) {
    L.wgS[tid]  = Wg[c0 + tid];
    L.vwgS[tid] = ws[OFF_VWG + tid];
    L.cS[tid]   = ws[OFF_C + tid];
  }
  for (int o = tid; o < 32*40; o += NT) {
    const int row = o / 40, cc = o % 40;
    L.inpA[row*296 + 256 + cc] =
        (cc < DDv) ? f2b(statc[(r0 + row)*DDv + cc]) : (unsigned short)0;
  }
  // Wd strip frags
  {
    int o = tid;
    if (o < 512) {
      const int slot = o >> 6, le = o & 63;
      const int ct = slot >> 2, kt = slot & 3;
      const int j = c0 + ct*16 + (le & 15);
      const int k0 = kt*32 + (le >> 4)*8;
      *(s8*)&L.wdF[o*8] = pack8(Wd + (size_t)j*XDv + k0);
    }
  }
  // valp strip frags (strided gather)
  if (tid < 128) {
    const int ct = tid >> 6, le = tid & 63;
    const int n = c0 + ct*16 + (le & 15);
    const int p0 = (le >> 4)*8;
    s8 r;
    #pragma unroll
    for (int e = 0; e < 8; ++e) r[e] = (short)f2b(ws[OFF_VALP + (size_t)(p0 + e)*Hv + n]);
    *(s8*)&L.vpF[tid*8] = r;
  }
  // M strip frags
  if (tid < 128) {
    const int nt = tid >> 6, le = tid & 63;
    const int p = nt*16 + (le & 15);
    const int k0 = c0 + (le >> 4)*8;
    *(s8*)&L.msF[tid*8] = pack8(ws + OFF_MF + (size_t)p*Hv + k0);
  }

  // ============ register weight preload ============
  const int xcol = wv*16 + l15;                 // this wave's x-column
  s8 whF[16]; s8 wfF[4]; s8 wBig[27];
  #pragma unroll
  for (int kt = 0; kt < 16; ++kt)
    whF[kt] = pack8(Wh + (size_t)xcol*Hv + kt*32 + l4*8);
  #pragma unroll
  for (int kt = 0; kt < 4; ++kt) {
    const int k0 = kt*32 + l4*8;
    s8 r = pack8(Wf + (size_t)xcol*XDv + k0);
    #pragma unroll
    for (int e = 0; e < 8; ++e) if (xcol == k0 + e) r[e] = 0;
    wfF[kt] = r;
  }
  if (wv < 6) {
    const int gc = wv*16 + l15;                 // gate-major col 0..95
    const int g = gc >> 5, jj = c0 + (gc & 31);
    #pragma unroll
    for (int kt = 0; kt < 16; ++kt)
      wBig[kt] = pack8(Whh + (size_t)(g*Hv + jj)*Hv + kt*32 + l4*8);
    #pragma unroll
    for (int kt = 16; kt < 27; ++kt) {
      s8 z; 
      #pragma unroll
      for (int e = 0; e < 8; ++e) z[e] = 0;
      wBig[kt] = z;
    }
  } else {
    #pragma unroll
    for (int cti = 0; cti < 3; ++cti) {
      const int ct = (wv - 6)*3 + cti;
      const int g = ct >> 1, jj = c0 + (ct & 1)*16 + l15;
      #pragma unroll
      for (int kt = 0; kt < 9; ++kt) {
        const int k0 = kt*32 + l4*8;
        s8 r;
        #pragma unroll
        for (int e = 0; e < 8; ++e) r[e] = 0;
        if (k0 <= 264) r = pack8(Wih + (size_t)(g*Hv + jj)*272 + k0);
        wBig[cti*9 + kt] = r;
      }
    }
  }
  // per-thread scalars
  const float bhR = bh[xcol], bfR = bf[xcol];
  int lensA[8];
  #pragma unroll
  for (int rt = 0; rt < 2; ++rt)
    #pragma unroll
    for (int i = 0; i < 4; ++i)
      lensA[rt*4 + i] = lens[r0 + rt*16 + l4*4 + i];
  const int art = wv >> 1, act = wv & 1;        // gamma/blend tile for waves 0-3
  const float bdR = (wv < 4) ? bd[c0 + act*16 + l15] : 0.f;
  const int crow = tid >> 5, cjj = tid & 31;    // GRU cell mapping (2 cells/thread)
  float bihR[3], bhhR[3];
  #pragma unroll
  for (int g = 0; g < 3; ++g) { bihR[g] = bih[g*Hv + c0 + cjj]; bhhR[g] = bhh[g*Hv + c0 + cjj]; }
  const int lensG0 = lens[r0 + crow], lensG1 = lens[r0 + crow + 16];
  const float bg0 = bg[0];
  __syncthreads();

  // ============ MAIN LOOP: 2 grid barriers / step ============
  for (int t = 0; t < Tv; ++t) {
    // ---- A1: sum score partials; stage times(t) ----
    if (proto) {
      for (int o = tid; o < 32*34; o += NT) {
        float s = 0.f;
        const float* p = wsSP + (size_t)rg*16*1088 + o;
        #pragma unroll 4
        for (int j = 0; j < 16; ++j) s += p[j*1088];
        L.scS[o] = s;
      }
    }
    {
      const int row = tid >> 4, k8 = (tid & 15)*8;
      *(s8*)&L.tA[row*136 + k8] =
          pack8(times + ((size_t)(r0 + row)*Tv + t)*XDv + k8);
    }
    __syncthreads();

    // ---- A2: softmax+alpha (wave 0) ----
    if (proto && wv == 0 && ln < 32) {
      const int r = ln;
      float mx = -1e30f;
      #pragma unroll 8
      for (int p = 0; p < 32; ++p)
        mx = fmaxf(mx, (L.scS[r*34 + p] + L.cS[p]) * scale);
      float sm = 0.f, a1 = 0.f;
      #pragma unroll 8
      for (int p = 0; p < 32; ++p) {
        float e = __expf((L.scS[r*34 + p] + L.cS[p]) * scale - mx);
        sm += e; a1 += e * L.vwgS[p];
        L.aA[r*40 + p] = f2b(e);
      }
      const float rs = 1.f / sm;
      L.rsm[r] = rs;
      L.al[r] = sig_f(L.scS[r*34 + 32] + a1*rs + bg0);
    }
    __syncthreads();

    // ---- A3: gamma (waves 0-3) + h1 (waves 4-7) ----
    f4 gam;
    if (wv < 4) {
      f4 acc = {0.f,0.f,0.f,0.f};
      #pragma unroll
      for (int kt = 0; kt < 4; ++kt) {
        s8 a = *(const s8*)&L.tA[(art*16 + l15)*136 + kt*32 + l4*8];
        s8 b = *(const s8*)&L.wdF[((act*4 + kt)*64 + ln)*8];
        acc = MFMA(a, b, acc);
      }
      #pragma unroll
      for (int i = 0; i < 4; ++i)
        gam[i] = __expf(-fmaxf(acc[i] + bdR, 0.f));
    } else if (proto) {
      const int rt = (wv - 4) >> 1, ct = (wv - 4) & 1;
      s8 a = *(const s8*)&L.aA[(rt*16 + l15)*40 + l4*8];
      s8 b = *(const s8*)&L.vpF[(ct*64 + ln)*8];
      f4 acc = {0.f,0.f,0.f,0.f};
      acc = MFMA(a, b, acc);
      #pragma unroll
      for (int i = 0; i < 4; ++i)
        L.h1S[(rt*16 + l4*4 + i)*33 + ct*16 + l15] = acc[i];
    }
    __syncthreads();

    // ---- A4: blend -> ws_hp (bf16) + hp32 (waves 0-3) ----
    if (wv < 4) {
      #pragma unroll
      for (int i = 0; i < 4; ++i) {
        const int row = art*16 + l4*4 + i;
        const int c = act*16 + l15;
        const float hv = L.hTile[row*33 + c];
        float hp;
        if (proto) {
          const float av = L.al[row];
          hp = (av*hv + (1.f - av)*L.h1S[row*33 + c]*L.rsm[row]) * gam[i];
        } else hp = hv * gam[i];
        wsHP[(size_t)(rg*32 + row)*Hv + c0 + c] = f2b(hp);
        L.hp32[row*32 + c] = hp;
      }
    }
    gridbar(bar, lgen, bid);   // B2: h' visible

    // ---- B1s: stage full h' rows ----
    for (int o = tid; o < 32*64; o += NT) {
      const int row = o >> 6, seg = o & 63;
      *(s8*)&L.hpA[row*520 + seg*8] =
          *(const s8*)&wsHP[(size_t)(rg*32 + row)*Hv + seg*8];
    }
    __syncthreads();

    // ---- B2s: x_h + x_c (all waves, own 16-col strip) ----
    float xvA[8], mvA[8];
    #pragma unroll
    for (int rt = 0; rt < 2; ++rt) {
      f4 acc = {0.f,0.f,0.f,0.f};
      #pragma unroll
      for (int kt = 0; kt < 16; ++kt) {
        s8 a = *(const s8*)&L.hpA[(rt*16 + l15)*520 + kt*32 + l4*8];
        acc = MFMA(a, whF[kt], acc);
      }
      #pragma unroll
      for (int i = 0; i < 4; ++i) {
        const int row = rt*16 + l4*4 + i;
        const int b = r0 + row;
        float xh = acc[i] + bhR;
        if (t < lensA[rt*4 + i]) L.xhS[row*128 + xcol] = xh;
        else                     xh = L.xhS[row*128 + xcol];
        const size_t xo = ((size_t)b*Tv + t)*XDv + xcol;
        const float xv = values[xo], mv = masks[xo];
        xvA[rt*4 + i] = xv; mvA[rt*4 + i] = mv;
        const float xc = mv*xv + (1.f - mv)*xh;
        if (cg == 0) out[OUT_XCS + xo] = xc;
        L.xcA[row*136 + xcol] = f2b(xc);
      }
    }
    __syncthreads();

    // ---- B3s: z_h + z_c -> inpA ----
    #pragma unroll
    for (int rt = 0; rt < 2; ++rt) {
      f4 acc = {0.f,0.f,0.f,0.f};
      #pragma unroll
      for (int kt = 0; kt < 4; ++kt) {
        s8 a = *(const s8*)&L.xcA[(rt*16 + l15)*136 + kt*32 + l4*8];
        acc = MFMA(a, wfF[kt], acc);
      }
      #pragma unroll
      for (int i = 0; i < 4; ++i) {
        const int row = rt*16 + l4*4 + i;
        const float xv = xvA[rt*4 + i], mv = mvA[rt*4 + i];
        const float zc = mv*xv + (1.f - mv)*(acc[i] + bfR);
        if (cg == 0) out[OUT_ZCS + ((size_t)(r0 + row)*Tv + t)*XDv + xcol] = zc;
        L.inpA[row*296 + xcol]       = f2b(zc);
        L.inpA[row*296 + 128 + xcol] = f2b(mv);
      }
    }
    __syncthreads();

    // ---- B4s: gh (waves 0-5) + gx (waves 6-7) ----
    if (wv < 6) {
      const int g = wv >> 1, cLoc = (wv & 1)*16 + l15;
      #pragma unroll
      for (int rt = 0; rt < 2; ++rt) {
        f4 acc = {0.f,0.f,0.f,0.f};
        #pragma unroll
        for (int kt = 0; kt < 16; ++kt) {
          s8 a = *(const s8*)&L.hpA[(rt*16 + l15)*520 + kt*32 + l4*8];
          acc = MFMA(a, wBig[kt], acc);
        }
        #pragma unroll
        for (int i = 0; i < 4; ++i)
          L.ghS[g*1056 + (rt*16 + l4*4 + i)*33 + cLoc] = acc[i];
      }
    } else {
      #pragma unroll
      for (int cti = 0; cti < 3; ++cti) {
        const int ct = (wv - 6)*3 + cti;
        const int g = ct >> 1, cLoc = (ct & 1)*16 + l15;
        #pragma unroll
        for (int rt = 0; rt < 2; ++rt) {
          f4 acc = {0.f,0.f,0.f,0.f};
          #pragma unroll
          for (int kt = 0; kt < 9; ++kt) {
            s8 a = *(const s8*)&L.inpA[(rt*16 + l15)*296 + kt*32 + l4*8];
            acc = MFMA(a, wBig[cti*9 + kt], acc);
          }
          #pragma unroll
          for (int i = 0; i < 4; ++i)
            L.gxS[g*1056 + (rt*16 + l4*4 + i)*33 + cLoc] = acc[i];
        }
      }
    }
    __syncthreads();

    // ---- B5s: GRU (2 cells/thread) ----
    #pragma unroll
    for (int cc = 0; cc < 2; ++cc) {
      const int row = crow + cc*16;
      const int b = r0 + row, jc = c0 + cjj;
      const float xr = L.gxS[row*33 + cjj]        + bihR[0];
      const float xz = L.gxS[1056 + row*33 + cjj] + bihR[1];
      const float xn = L.gxS[2112 + row*33 + cjj] + bihR[2];
      const float hr = L.ghS[row*33 + cjj]        + bhhR[0];
      const float hz = L.ghS[1056 + row*33 + cjj] + bhhR[1];
      const float hn = L.ghS[2112 + row*33 + cjj] + bhhR[2];
      const float r = sig_f(xr + hr), z = sig_f(xz + hz);
      const float n = tanh_f(xn + r*hn);
      const float hpv = L.hp32[row*32 + cjj];
      const int lb = cc ? lensG1 : lensG0;
      const float hfv = (t < lb) ? ((1.f - z)*n + z*hpv) : hpv;
      L.hTile[row*33 + cjj] = hfv;
      L.hTileB[row*40 + cjj] = f2b(hfv);
      out[OUT_HS + ((size_t)b*Tv + t)*Hv + jc] = hfv;
      if (t == Tv - 1) out[OUT_HN + (size_t)b*Hv + jc] = hfv;
    }
    __syncthreads();

    // ---- B6s: score partials (waves 6,7) + ah partial (wave 4) ----
    if (proto) {
      if (wv >= 6) {
        const int nt = wv - 6;
        #pragma unroll
        for (int rt = 0; rt < 2; ++rt) {
          s8 a = *(const s8*)&L.hTileB[(rt*16 + l15)*40 + l4*8];
          s8 b = *(const s8*)&L.msF[(nt*64 + ln)*8];
          f4 acc = {0.f,0.f,0.f,0.f};
          acc = MFMA(a, b, acc);
          #pragma unroll
          for (int i = 0; i < 4; ++i)
            wsSP[(size_t)(rg*16 + cg)*1088 + (rt*16 + l4*4 + i)*34 + nt*16 + l15] = acc[i];
        }
      } else if (wv == 4) {
        const int r = ln >> 1, hh = ln & 1;
        float s = 0.f;
        #pragma unroll
        for (int k = 0; k < 16; ++k)
          s += L.hTile[r*33 + hh*16 + k] * L.wgS[hh*16 + k];
        s += __shfl_xor(s, 1);
        if (hh == 0) wsSP[(size_t)(rg*16 + cg)*1088 + r*34 + 32] = s;
      }
    }
    gridbar(bar, lgen, bid);   // B1: h-partials visible for next step
  }
}

extern "C" void kernel_launch(void* const* d_in, const int* in_sizes, int n_in,
                              void* d_out, int out_size, void* d_ws, size_t ws_size,
                              hipStream_t stream) {
  (void)in_sizes; (void)n_in; (void)out_size; (void)ws_size;
  hipMemsetAsync(d_ws, 0, 4096, stream);
  rits_main<<<NB, NT, 0, stream>>>(
      (const float*)d_in[0],  (const int*)d_in[1],   (const float*)d_in[2],
      (const float*)d_in[3],  (const float*)d_in[4], (const float*)d_in[5],
      (const int*)d_in[6],
      (const float*)d_in[7],  (const float*)d_in[8],
      (const float*)d_in[9],  (const float*)d_in[10],
      (const float*)d_in[11], (const float*)d_in[12],
      (const float*)d_in[13], (const float*)d_in[14],
      (const float*)d_in[15], (const float*)d_in[16],
      (const float*)d_in[17], (const float*)d_in[18],
      (const float*)d_in[19], (const float*)d_in[20],
      (const float*)d_in[21], (const float*)d_in[22],
      (const float*)d_in[23], (const float*)d_in[24],
      (float*)d_out, (float*)d_ws);
}

// Round 5
// 21454.169 us; speedup vs baseline: 3.8843x; 1.0465x over previous
//
#include <hip/hip_runtime.h>

#define NB 256
#define NT 512

#define Bv 512
#define Tv 256
#define XDv 128
#define Hv 512
#define DDv 16
#define Pv 32

typedef short s8 __attribute__((ext_vector_type(8)));
typedef float f4 __attribute__((ext_vector_type(4)));

// ---- ws float offsets ----
#define OFF_KEYP 1024
#define OFF_VALP (OFF_KEYP + 16384)
#define OFF_MF   (OFF_VALP + 16384)
#define OFF_C    (OFF_MF + 16384)
#define OFF_VWG  (OFF_C + 32)
#define OFF_SP   (OFF_VWG + 32)
#define SP_SZ    (16*16*32*34)          // [rg][cg][32 rows][34] f32 partials
#define OFF_HPX  (OFF_SP + SP_SZ)       // bf16 [16][32][512] h' exchange

// ---- out offsets ----
#define OUT_HS  0
#define OUT_HN  (Bv*Tv*Hv)
#define OUT_XCS (OUT_HN + Bv*Hv)
#define OUT_ZCS (OUT_XCS + Bv*Tv*XDv)

struct Smem {
  unsigned short hpA[32*520];   // full h' rows bf16 (staged from ws each step)
  unsigned short tA[32*136];    // times(t) bf16
  unsigned short xcA[32*136];   // x_c bf16
  unsigned short inpA[32*296];  // [z_c | m | static | 0pad] bf16
  unsigned short aA[32*40];     // exp(score) bf16
  unsigned short hTileB[32*40]; // h tile bf16 (A-frag for score partials)
  unsigned short wdF[8*64*8];   // Wd strip frags
  unsigned short vpF[2*64*8];   // valp strip frags
  unsigned short msF[2*64*8];   // M strip frags
  float xhS[32*128];            // persistent x_h state (this row-group)
  float hTile[32*33];           // h tile f32 (persistent across steps)
  float scS[32*34];             // summed scores (+ah at col 32)
  float h1S[32*33];
  float ghS[3*32*33];
  float gxS[3*32*33];
  float hp32[32*32];            // h' f32 own col-tile (GRU carry)
  float al[32], rsm[32], wgS[32], vwgS[32], cS[32];
};

__device__ __forceinline__ unsigned short f2b(float f) {
  union { float f; unsigned int u; } x{f};
  unsigned int r = x.u + 0x7fffu + ((x.u >> 16) & 1u);
  return (unsigned short)(r >> 16);
}
__device__ __forceinline__ float sig_f(float x) { return 1.f / (1.f + __expf(-x)); }
__device__ __forceinline__ float tanh_f(float x) {
  x = fminf(fmaxf(x, -15.f), 15.f);
  float e = __expf(2.f * x);
  return (e - 1.f) / (e + 1.f);
}

__device__ __forceinline__ s8 pack8(const float* p) {
  f4 a = *(const f4*)p; f4 b = *(const f4*)(p + 4);
  s8 r;
  r[0]=(short)f2b(a[0]); r[1]=(short)f2b(a[1]); r[2]=(short)f2b(a[2]); r[3]=(short)f2b(a[3]);
  r[4]=(short)f2b(b[0]); r[5]=(short)f2b(b[1]); r[6]=(short)f2b(b[2]); r[7]=(short)f2b(b[3]);
  return r;
}

// two-level grid barrier: 16 arrival lines + root; relaxed polls
__device__ __forceinline__ void gridbar(unsigned int* bar, unsigned int& lgen, int bid) {
  __syncthreads();
  if (threadIdx.x == 0) {
    __threadfence();
    const unsigned int target = ++lgen;
    unsigned int* grp = bar + (bid >> 4)*16;
    const unsigned int a =
        __hip_atomic_fetch_add(grp, 1u, __ATOMIC_ACQ_REL, __HIP_MEMORY_SCOPE_AGENT);
    if (a == 15u) {
      __hip_atomic_store(grp, 0u, __ATOMIC_RELAXED, __HIP_MEMORY_SCOPE_AGENT);
      const unsigned int r =
          __hip_atomic_fetch_add(bar + 256, 1u, __ATOMIC_ACQ_REL, __HIP_MEMORY_SCOPE_AGENT);
      if (r == 15u) {
        __hip_atomic_store(bar + 256, 0u, __ATOMIC_RELAXED, __HIP_MEMORY_SCOPE_AGENT);
        __hip_atomic_store(bar + 272, target, __ATOMIC_RELEASE, __HIP_MEMORY_SCOPE_AGENT);
      }
    }
    while (__hip_atomic_load(bar + 272, __ATOMIC_RELAXED, __HIP_MEMORY_SCOPE_AGENT) < target)
      __builtin_amdgcn_s_sleep(2);
    __threadfence();
  }
  __syncthreads();
}

#define MFMA(a,b,c) __builtin_amdgcn_mfma_f32_16x16x32_bf16((a),(b),(c),0,0,0)

// 512 threads, min 2 waves/EU -> 1 block/CU, 256-VGPR budget (HIP: 2nd arg is waves/EU)
__global__ __launch_bounds__(NT, 2)
void rits_main(const float* __restrict__ values, const int* __restrict__ lens,
               const float* __restrict__ statc, const float* __restrict__ times,
               const float* __restrict__ masks, const float* __restrict__ prototype,
               const int* __restrict__ protoflag,
               const float* __restrict__ Wd, const float* __restrict__ bd,
               const float* __restrict__ Wh, const float* __restrict__ bh,
               const float* __restrict__ Wf, const float* __restrict__ bf,
               const float* __restrict__ Wq, const float* __restrict__ bq,
               const float* __restrict__ Wk, const float* __restrict__ bk,
               const float* __restrict__ Wv, const float* __restrict__ bv,
               const float* __restrict__ Wg, const float* __restrict__ bg,
               const float* __restrict__ Wih, const float* __restrict__ Whh,
               const float* __restrict__ bih, const float* __restrict__ bhh,
               float* __restrict__ out, float* __restrict__ ws)
{
  const int bid = blockIdx.x, tid = threadIdx.x;
  const int gtid = bid*NT + tid;
  const int wv = tid >> 6, ln = tid & 63;
  const int l15 = ln & 15, l4 = ln >> 4;
  const int rg = bid >> 4, cg = bid & 15;
  const int r0 = rg*32, c0 = cg*32;
  unsigned int* bar = (unsigned int*)ws;
  unsigned int lgen = 0;
  unsigned short* wsHP = (unsigned short*)(ws + OFF_HPX);
  float* wsSP = ws + OFF_SP;

  __shared__ Smem L;
  const bool proto = protoflag[0] != 0;
  const float scale = 0.17677669529663687f;

  // ============ INIT 1: keyp/valp + zero ws_sp ============
  for (int o = gtid; o < SP_SZ; o += NB*NT) wsSP[o] = 0.f;
  for (int o = gtid; o < 2*Pv*Hv; o += NB*NT) {
    const int which = o >> 14, rem = o & 16383;
    const int p = rem >> 9, j = rem & 511;
    const float* W = which ? Wv : Wk;
    const float* bb = which ? bv : bk;
    const float* pr = prototype + p*Hv;
    const float* wr = W + j*Hv;
    float s = bb[j];
    #pragma unroll 4
    for (int k = 0; k < Hv; ++k) s += pr[k]*wr[k];
    ws[(which ? OFF_VALP : OFF_KEYP) + p*Hv + j] = s;
  }
  gridbar(bar, lgen, bid);

  // ============ INIT 2: M = keyp@Wq, c, vwg ============
  {
    const float* keyp = ws + OFF_KEYP;
    const float* valp = ws + OFF_VALP;
    for (int o = gtid; o < Pv*Hv; o += NB*NT) {
      const int p = o >> 9, kc = o & 511;
      float s = 0.f;
      #pragma unroll 4
      for (int j = 0; j < Hv; ++j) s += keyp[p*Hv + j]*Wq[j*Hv + kc];
      ws[OFF_MF + o] = s;
    }
    if (gtid < 32) {
      float s = 0.f;
      for (int j = 0; j < Hv; ++j) s += bq[j]*keyp[gtid*Hv + j];
      ws[OFF_C + gtid] = s;
    } else if (gtid < 64) {
      const int p = gtid - 32;
      float s = 0.f;
      for (int j = 0; j < Hv; ++j) s += valp[p*Hv + j]*Wg[Hv + j];
      ws[OFF_VWG + p] = s;
    }
  }
  gridbar(bar, lgen, bid);

  // ============ block-local LDS init ============
  for (int o = tid; o < 32*33; o += NT) L.hTile[o] = 0.f;
  for (int o = tid; o < 32*128; o += NT) L.xhS[o] = 0.f;
  if (tid < 32) {
    L.wgS[tid]  = Wg[c0 + tid];
    L.vwgS[tid] = ws[OFF_VWG + tid];
    L.cS[tid]   = ws[OFF_C + tid];
  }
  for (int o = tid; o < 32*40; o += NT) {
    const int row = o / 40, cc = o % 40;
    L.inpA[row*296 + 256 + cc] =
        (cc < DDv) ? f2b(statc[(r0 + row)*DDv + cc]) : (unsigned short)0;
  }
  // Wd strip frags
  if (tid < 512) {
    const int slot = tid >> 6, le = tid & 63;
    const int ct = slot >> 2, kt = slot & 3;
    const int j = c0 + ct*16 + (le & 15);
    const int k0 = kt*32 + (le >> 4)*8;
    *(s8*)&L.wdF[tid*8] = pack8(Wd + (size_t)j*XDv + k0);
  }
  // valp strip frags (strided gather)
  if (tid < 128) {
    const int ct = tid >> 6, le = tid & 63;
    const int n = c0 + ct*16 + (le & 15);
    const int p0 = (le >> 4)*8;
    s8 r;
    #pragma unroll
    for (int e = 0; e < 8; ++e) r[e] = (short)f2b(ws[OFF_VALP + (size_t)(p0 + e)*Hv + n]);
    *(s8*)&L.vpF[tid*8] = r;
  }
  // M strip frags
  if (tid < 128) {
    const int nt = tid >> 6, le = tid & 63;
    const int p = nt*16 + (le & 15);
    const int k0 = c0 + (le >> 4)*8;
    *(s8*)&L.msF[tid*8] = pack8(ws + OFF_MF + (size_t)p*Hv + k0);
  }

  // ============ register weight preload ============
  const int xcol = wv*16 + l15;                 // this wave's x-column
  s8 whF[16]; s8 wfF[4]; s8 wBig[27];
  #pragma unroll
  for (int kt = 0; kt < 16; ++kt)
    whF[kt] = pack8(Wh + (size_t)xcol*Hv + kt*32 + l4*8);
  #pragma unroll
  for (int kt = 0; kt < 4; ++kt) {
    const int k0 = kt*32 + l4*8;
    s8 r = pack8(Wf + (size_t)xcol*XDv + k0);
    #pragma unroll
    for (int e = 0; e < 8; ++e) if (xcol == k0 + e) r[e] = 0;
    wfF[kt] = r;
  }
  if (wv < 6) {
    const int gc = wv*16 + l15;                 // gate-major col 0..95
    const int g = gc >> 5, jj = c0 + (gc & 31);
    #pragma unroll
    for (int kt = 0; kt < 16; ++kt)
      wBig[kt] = pack8(Whh + (size_t)(g*Hv + jj)*Hv + kt*32 + l4*8);
    #pragma unroll
    for (int kt = 16; kt < 27; ++kt) {
      s8 z;
      #pragma unroll
      for (int e = 0; e < 8; ++e) z[e] = 0;
      wBig[kt] = z;
    }
  } else {
    #pragma unroll
    for (int cti = 0; cti < 3; ++cti) {
      const int ct = (wv - 6)*3 + cti;
      const int g = ct >> 1, jj = c0 + (ct & 1)*16 + l15;
      #pragma unroll
      for (int kt = 0; kt < 9; ++kt) {
        const int k0 = kt*32 + l4*8;
        s8 r;
        #pragma unroll
        for (int e = 0; e < 8; ++e) r[e] = 0;
        if (k0 <= 264) r = pack8(Wih + (size_t)(g*Hv + jj)*272 + k0);
        wBig[cti*9 + kt] = r;
      }
    }
  }
  // per-thread scalars
  const float bhR = bh[xcol], bfR = bf[xcol];
  int lensA[8];
  #pragma unroll
  for (int rt = 0; rt < 2; ++rt)
    #pragma unroll
    for (int i = 0; i < 4; ++i)
      lensA[rt*4 + i] = lens[r0 + rt*16 + l4*4 + i];
  const int art = wv >> 1, act = wv & 1;        // gamma/blend tile for waves 0-3
  const float bdR = (wv < 4) ? bd[c0 + act*16 + l15] : 0.f;
  const int crow = tid >> 5, cjj = tid & 31;    // GRU cell mapping (2 cells/thread)
  float bihR[3], bhhR[3];
  #pragma unroll
  for (int g = 0; g < 3; ++g) { bihR[g] = bih[g*Hv + c0 + cjj]; bhhR[g] = bhh[g*Hv + c0 + cjj]; }
  const int lensG0 = lens[r0 + crow], lensG1 = lens[r0 + crow + 16];
  const float bg0 = bg[0];
  __syncthreads();

  // ============ MAIN LOOP: 2 grid barriers / step ============
  for (int t = 0; t < Tv; ++t) {
    // ---- A1: sum score partials; stage times(t) ----
    if (proto) {
      for (int o = tid; o < 32*34; o += NT) {
        float s = 0.f;
        const float* p = wsSP + (size_t)rg*16*1088 + o;
        #pragma unroll 4
        for (int j = 0; j < 16; ++j) s += p[j*1088];
        L.scS[o] = s;
      }
    }
    {
      const int row = tid >> 4, k8 = (tid & 15)*8;
      *(s8*)&L.tA[row*136 + k8] =
          pack8(times + ((size_t)(r0 + row)*Tv + t)*XDv + k8);
    }
    __syncthreads();

    // ---- A2: softmax+alpha (wave 0) ----
    if (proto && wv == 0 && ln < 32) {
      const int r = ln;
      float mx = -1e30f;
      #pragma unroll 8
      for (int p = 0; p < 32; ++p)
        mx = fmaxf(mx, (L.scS[r*34 + p] + L.cS[p]) * scale);
      float sm = 0.f, a1 = 0.f;
      #pragma unroll 8
      for (int p = 0; p < 32; ++p) {
        float e = __expf((L.scS[r*34 + p] + L.cS[p]) * scale - mx);
        sm += e; a1 += e * L.vwgS[p];
        L.aA[r*40 + p] = f2b(e);
      }
      const float rs = 1.f / sm;
      L.rsm[r] = rs;
      L.al[r] = sig_f(L.scS[r*34 + 32] + a1*rs + bg0);
    }
    __syncthreads();

    // ---- A3: gamma (waves 0-3) + h1 (waves 4-7) ----
    f4 gam;
    if (wv < 4) {
      f4 acc = {0.f,0.f,0.f,0.f};
      #pragma unroll
      for (int kt = 0; kt < 4; ++kt) {
        s8 a = *(const s8*)&L.tA[(art*16 + l15)*136 + kt*32 + l4*8];
        s8 b = *(const s8*)&L.wdF[((act*4 + kt)*64 + ln)*8];
        acc = MFMA(a, b, acc);
      }
      #pragma unroll
      for (int i = 0; i < 4; ++i)
        gam[i] = __expf(-fmaxf(acc[i] + bdR, 0.f));
    } else if (proto) {
      const int rt = (wv - 4) >> 1, ct = (wv - 4) & 1;
      s8 a = *(const s8*)&L.aA[(rt*16 + l15)*40 + l4*8];
      s8 b = *(const s8*)&L.vpF[(ct*64 + ln)*8];
      f4 acc = {0.f,0.f,0.f,0.f};
      acc = MFMA(a, b, acc);
      #pragma unroll
      for (int i = 0; i < 4; ++i)
        L.h1S[(rt*16 + l4*4 + i)*33 + ct*16 + l15] = acc[i];
    }
    __syncthreads();

    // ---- A4: blend -> ws_hp (bf16) + hp32 (waves 0-3) ----
    if (wv < 4) {
      #pragma unroll
      for (int i = 0; i < 4; ++i) {
        const int row = art*16 + l4*4 + i;
        const int c = act*16 + l15;
        const float hv = L.hTile[row*33 + c];
        float hp;
        if (proto) {
          const float av = L.al[row];
          hp = (av*hv + (1.f - av)*L.h1S[row*33 + c]*L.rsm[row]) * gam[i];
        } else hp = hv * gam[i];
        wsHP[(size_t)(rg*32 + row)*Hv + c0 + c] = f2b(hp);
        L.hp32[row*32 + c] = hp;
      }
    }
    gridbar(bar, lgen, bid);   // h' visible

    // ---- B1s: stage full h' rows ----
    for (int o = tid; o < 32*64; o += NT) {
      const int row = o >> 6, seg = o & 63;
      *(s8*)&L.hpA[row*520 + seg*8] =
          *(const s8*)&wsHP[(size_t)(rg*32 + row)*Hv + seg*8];
    }
    __syncthreads();

    // ---- B2s: x_h + x_c (all waves, own 16-col strip) ----
    #pragma unroll
    for (int rt = 0; rt < 2; ++rt) {
      f4 acc = {0.f,0.f,0.f,0.f};
      #pragma unroll
      for (int kt = 0; kt < 16; ++kt) {
        s8 a = *(const s8*)&L.hpA[(rt*16 + l15)*520 + kt*32 + l4*8];
        acc = MFMA(a, whF[kt], acc);
      }
      #pragma unroll
      for (int i = 0; i < 4; ++i) {
        const int row = rt*16 + l4*4 + i;
        const int b = r0 + row;
        float xh = acc[i] + bhR;
        if (t < lensA[rt*4 + i]) L.xhS[row*128 + xcol] = xh;
        else                     xh = L.xhS[row*128 + xcol];
        const size_t xo = ((size_t)b*Tv + t)*XDv + xcol;
        const float xv = values[xo], mv = masks[xo];
        const float xc = mv*xv + (1.f - mv)*xh;
        if (cg == 0) out[OUT_XCS + xo] = xc;
        L.xcA[row*136 + xcol] = f2b(xc);
      }
    }
    __syncthreads();

    // ---- B3s: z_h + z_c -> inpA (re-read values/masks: L1/L2-hot) ----
    #pragma unroll
    for (int rt = 0; rt < 2; ++rt) {
      f4 acc = {0.f,0.f,0.f,0.f};
      #pragma unroll
      for (int kt = 0; kt < 4; ++kt) {
        s8 a = *(const s8*)&L.xcA[(rt*16 + l15)*136 + kt*32 + l4*8];
        acc = MFMA(a, wfF[kt], acc);
      }
      #pragma unroll
      for (int i = 0; i < 4; ++i) {
        const int row = rt*16 + l4*4 + i;
        const size_t xo = ((size_t)(r0 + row)*Tv + t)*XDv + xcol;
        const float xv = values[xo], mv = masks[xo];
        const float zc = mv*xv + (1.f - mv)*(acc[i] + bfR);
        if (cg == 0) out[OUT_ZCS + xo] = zc;
        L.inpA[row*296 + xcol]       = f2b(zc);
        L.inpA[row*296 + 128 + xcol] = f2b(mv);
      }
    }
    __syncthreads();

    // ---- B4s: gh (waves 0-5) + gx (waves 6-7) ----
    if (wv < 6) {
      const int g = wv >> 1, cLoc = (wv & 1)*16 + l15;
      #pragma unroll
      for (int rt = 0; rt < 2; ++rt) {
        f4 acc = {0.f,0.f,0.f,0.f};
        #pragma unroll
        for (int kt = 0; kt < 16; ++kt) {
          s8 a = *(const s8*)&L.hpA[(rt*16 + l15)*520 + kt*32 + l4*8];
          acc = MFMA(a, wBig[kt], acc);
        }
        #pragma unroll
        for (int i = 0; i < 4; ++i)
          L.ghS[g*1056 + (rt*16 + l4*4 + i)*33 + cLoc] = acc[i];
      }
    } else {
      #pragma unroll
      for (int cti = 0; cti < 3; ++cti) {
        const int ct = (wv - 6)*3 + cti;
        const int g = ct >> 1, cLoc = (ct & 1)*16 + l15;
        #pragma unroll
        for (int rt = 0; rt < 2; ++rt) {
          f4 acc = {0.f,0.f,0.f,0.f};
          #pragma unroll
          for (int kt = 0; kt < 9; ++kt) {
            s8 a = *(const s8*)&L.inpA[(rt*16 + l15)*296 + kt*32 + l4*8];
            acc = MFMA(a, wBig[cti*9 + kt], acc);
          }
          #pragma unroll
          for (int i = 0; i < 4; ++i)
            L.gxS[g*1056 + (rt*16 + l4*4 + i)*33 + cLoc] = acc[i];
        }
      }
    }
    __syncthreads();

    // ---- B5s: GRU (2 cells/thread) ----
    #pragma unroll
    for (int cc = 0; cc < 2; ++cc) {
      const int row = crow + cc*16;
      const int b = r0 + row, jc = c0 + cjj;
      const float xr = L.gxS[row*33 + cjj]        + bihR[0];
      const float xz = L.gxS[1056 + row*33 + cjj] + bihR[1];
      const float xn = L.gxS[2112 + row*33 + cjj] + bihR[2];
      const float hr = L.ghS[row*33 + cjj]        + bhhR[0];
      const float hz = L.ghS[1056 + row*33 + cjj] + bhhR[1];
      const float hn = L.ghS[2112 + row*33 + cjj] + bhhR[2];
      const float r = sig_f(xr + hr), z = sig_f(xz + hz);
      const float n = tanh_f(xn + r*hn);
      const float hpv = L.hp32[row*32 + cjj];
      const int lb = cc ? lensG1 : lensG0;
      const float hfv = (t < lb) ? ((1.f - z)*n + z*hpv) : hpv;
      L.hTile[row*33 + cjj] = hfv;
      L.hTileB[row*40 + cjj] = f2b(hfv);
      out[OUT_HS + ((size_t)b*Tv + t)*Hv + jc] = hfv;
      if (t == Tv - 1) out[OUT_HN + (size_t)b*Hv + jc] = hfv;
    }
    __syncthreads();

    // ---- B6s: score partials (waves 6,7) + ah partial (wave 4) ----
    if (proto) {
      if (wv >= 6) {
        const int nt = wv - 6;
        #pragma unroll
        for (int rt = 0; rt < 2; ++rt) {
          s8 a = *(const s8*)&L.hTileB[(rt*16 + l15)*40 + l4*8];
          s8 b = *(const s8*)&L.msF[(nt*64 + ln)*8];
          f4 acc = {0.f,0.f,0.f,0.f};
          acc = MFMA(a, b, acc);
          #pragma unroll
          for (int i = 0; i < 4; ++i)
            wsSP[(size_t)(rg*16 + cg)*1088 + (rt*16 + l4*4 + i)*34 + nt*16 + l15] = acc[i];
        }
      } else if (wv == 4) {
        const int r = ln >> 1, hh = ln & 1;
        float s = 0.f;
        #pragma unroll
        for (int k = 0; k < 16; ++k)
          s += L.hTile[r*33 + hh*16 + k] * L.wgS[hh*16 + k];
        s += __shfl_xor(s, 1);
        if (hh == 0) wsSP[(size_t)(rg*16 + cg)*1088 + r*34 + 32] = s;
      }
    }
    gridbar(bar, lgen, bid);   // partials visible for next step
  }
}

extern "C" void kernel_launch(void* const* d_in, const int* in_sizes, int n_in,
                              void* d_out, int out_size, void* d_ws, size_t ws_size,
                              hipStream_t stream) {
  (void)in_sizes; (void)n_in; (void)out_size; (void)ws_size;
  hipMemsetAsync(d_ws, 0, 4096, stream);
  rits_main<<<NB, NT, 0, stream>>>(
      (const float*)d_in[0],  (const int*)d_in[1],   (const float*)d_in[2],
      (const float*)d_in[3],  (const float*)d_in[4], (const float*)d_in[5],
      (const int*)d_in[6],
      (const float*)d_in[7],  (const float*)d_in[8],
      (const float*)d_in[9],  (const float*)d_in[10],
      (const float*)d_in[11], (const float*)d_in[12],
      (const float*)d_in[13], (const float*)d_in[14],
      (const float*)d_in[15], (const float*)d_in[16],
      (const float*)d_in[17], (const float*)d_in[18],
      (const float*)d_in[19], (const float*)d_in[20],
      (const float*)d_in[21], (const float*)d_in[22],
      (const float*)d_in[23], (const float*)d_in[24],
      (float*)d_out, (float*)d_ws);
}